// Round 1
// baseline (536.539 us; speedup 1.0000x reference)
//
#include <hip/hip_runtime.h>
#include <hip/hip_bf16.h>

// ---------------- problem constants ----------------
#define B_    256
#define T_    250
#define NIN   700
#define NHID  512
#define NOUT  20
#define KT_N  11                 // k-tiles of 64 per segment: 704 = 11*64
#define MC_N  2000               // 64000 / 32 row-chunks
#define M_TOT (B_ * T_)          // 64000

typedef float  f32x2  __attribute__((ext_vector_type(2)));
typedef float  f32x4  __attribute__((ext_vector_type(4)));
typedef float  f32x16 __attribute__((ext_vector_type(16)));
typedef int    i32x2  __attribute__((ext_vector_type(2)));
typedef int    i32x4  __attribute__((ext_vector_type(4)));
typedef int    i32x8  __attribute__((ext_vector_type(8)));

// ---------------- workspace layout ----------------
// [0, 65,536,000)   : i_in  (M_TOT x NHID bf16)
// [+, 180,224,000)  : Apack fp8 fragment-major, ALL 4 segs precomputed
//                     word index = ((kt*MC_N + mc)*4 + seg)*512 + t*2
// [+, 1,441,792)    : Bpack fp8 fragment-major (4 segs)
// [+, 1,048,576)    : w_recT (512x512 f32)
// total ~248.3 MB
#define IIN_BYTES   ((size_t)M_TOT * NHID * 2)
#define APACK_OFF   IIN_BYTES
#define APACK_BYTES ((size_t)KT_N * MC_N * 4 * 2048)
#define BPACK_OFF   (APACK_OFF + APACK_BYTES)
#define BPACK_BYTES ((size_t)4 * KT_N * 16 * 64 * 32)
#define BPACK_WORDS (BPACK_BYTES / 4)                  // 360,448
#define WRECT_OFF   (BPACK_OFF + BPACK_BYTES)
#define BSEG        (KT_N * 16 * 512)                  // 90,112 words per B seg

// ---------------- kernel 1: pack B to fp8 fragment-major + transpose w_rec ----------------
__global__ __launch_bounds__(256) void kan_pack(
    const float* __restrict__ w_kan, const float* __restrict__ d1,
    const float* __restrict__ d2,    const float* __restrict__ d3,
    const float* __restrict__ w_rec,
    int* __restrict__ BpackW, float* __restrict__ wrecT)
{
    int idx = blockIdx.x * 256 + threadIdx.x;
    if (idx < (int)BPACK_WORDS) {
        int w   = idx;
        int c   = w >> 3;                  // 32-byte chunk index
        int jj  = (w & 7) * 4;             // byte offset within chunk
        int ln  = c & 31;
        int kh  = (c >> 5) & 1;
        int nt  = (c >> 6) & 15;
        int ks  = c >> 10;                 // seg*11 + kt
        int kt  = ks % 11;
        int seg = ks / 11;
        int n   = nt * 32 + ln;
        int kb  = kt * 64 + kh * 32 + jj;
        const float* wp = (seg == 0) ? w_kan : (seg == 1) ? d1 : (seg == 2) ? d2 : d3;
        float f0 = (kb + 0 < NIN) ? wp[(size_t)n * NIN + kb + 0] : 0.0f;
        float f1 = (kb + 1 < NIN) ? wp[(size_t)n * NIN + kb + 1] : 0.0f;
        float f2 = (kb + 2 < NIN) ? wp[(size_t)n * NIN + kb + 2] : 0.0f;
        float f3 = (kb + 3 < NIN) ? wp[(size_t)n * NIN + kb + 3] : 0.0f;
        int u = __builtin_amdgcn_cvt_pk_fp8_f32(f0, f1, 0, false);
        u     = __builtin_amdgcn_cvt_pk_fp8_f32(f2, f3, u, true);
        BpackW[w] = u;
    }
    if (idx < NHID * NHID) {
        int h  = idx & 511;
        int hp = idx >> 9;
        wrecT[(size_t)hp * NHID + h] = w_rec[(size_t)h * NHID + hp];
    }
}

// ---------------- kernel 2: pack x AND t1/t2/t3 to fp8 A-fragment-major ----------------
// t-powers computed here from full-precision x (no fp8 decode needed), so the GEMM
// inner loop is pure load+MFMA. Block = one (mc, kt): 32 rows x 64 k.
// Thread t=(kh,r,q) reads 8 floats, writes 8 fp8 bytes per segment (coalesced per seg).
__global__ __launch_bounds__(256) void kan_packa(
    const float* __restrict__ x, int* __restrict__ Apack)
{
    int blk = blockIdx.x;          // mc*11 + kt
    int kt  = blk % KT_N;
    int mc  = blk / KT_N;
    int t   = threadIdx.x;
    int q   = t & 3;
    int r   = (t >> 2) & 31;
    int kh  = t >> 7;
    int k0  = kt * 64 + kh * 32 + q * 8;      // max 696
    const float* xr = x + (size_t)(mc * 32 + r) * NIN + k0;
    f32x4 v0 = *(const f32x4*)xr;             // always in-range (k0+3 <= 699)
    f32x4 v1 = {0.f, 0.f, 0.f, 0.f};
    if (k0 + 7 < NIN) v1 = *(const f32x4*)(xr + 4);

    float e[8] = {v0[0], v0[1], v0[2], v0[3], v1[0], v1[1], v1[2], v1[3]};
    float p1[8], p2[8], p3[8];
    #pragma unroll
    for (int u = 0; u < 8; ++u) {
        p1[u] = fminf(fabsf(e[u]), 1.0f);     // t1 = clip(|x|,0,1)
        p2[u] = p1[u] * p1[u];
        p3[u] = p2[u] * p1[u];
    }

    int* base = Apack + ((size_t)(kt * MC_N + mc)) * 2048 + t * 2;
    // seg 0: raw x
    {
        int u0 = __builtin_amdgcn_cvt_pk_fp8_f32(e[0], e[1], 0, false);
        u0     = __builtin_amdgcn_cvt_pk_fp8_f32(e[2], e[3], u0, true);
        int u1 = __builtin_amdgcn_cvt_pk_fp8_f32(e[4], e[5], 0, false);
        u1     = __builtin_amdgcn_cvt_pk_fp8_f32(e[6], e[7], u1, true);
        *(i32x2*)base = i32x2{u0, u1};
    }
    // seg 1: t1
    {
        int u0 = __builtin_amdgcn_cvt_pk_fp8_f32(p1[0], p1[1], 0, false);
        u0     = __builtin_amdgcn_cvt_pk_fp8_f32(p1[2], p1[3], u0, true);
        int u1 = __builtin_amdgcn_cvt_pk_fp8_f32(p1[4], p1[5], 0, false);
        u1     = __builtin_amdgcn_cvt_pk_fp8_f32(p1[6], p1[7], u1, true);
        *(i32x2*)(base + 512) = i32x2{u0, u1};
    }
    // seg 2: t1^2
    {
        int u0 = __builtin_amdgcn_cvt_pk_fp8_f32(p2[0], p2[1], 0, false);
        u0     = __builtin_amdgcn_cvt_pk_fp8_f32(p2[2], p2[3], u0, true);
        int u1 = __builtin_amdgcn_cvt_pk_fp8_f32(p2[4], p2[5], 0, false);
        u1     = __builtin_amdgcn_cvt_pk_fp8_f32(p2[6], p2[7], u1, true);
        *(i32x2*)(base + 1024) = i32x2{u0, u1};
    }
    // seg 3: t1^3
    {
        int u0 = __builtin_amdgcn_cvt_pk_fp8_f32(p3[0], p3[1], 0, false);
        u0     = __builtin_amdgcn_cvt_pk_fp8_f32(p3[2], p3[3], u0, true);
        int u1 = __builtin_amdgcn_cvt_pk_fp8_f32(p3[4], p3[5], 0, false);
        u1     = __builtin_amdgcn_cvt_pk_fp8_f32(p3[6], p3[7], u1, true);
        *(i32x2*)(base + 1536) = i32x2{u0, u1};
    }
}

// ---------------- kernel 3: barrier-free fp8 GEMM, pure load+MFMA inner loop ----------------
// i_in = [x|t1|t1^2|t1^3] @ [w_kan|d1|d2|d3]^T via mfma_scale_f32_32x32x64_f8f6f4.
// Block 128x128, 4 waves (2x2 of 64x64), wave = 2x2 of 32x32x64.
// All 4 A segments read pre-packed from Apack; no decode/repack VALU work.
// XCD-chunked swizzle keeps the 4 ntile-blocks of one A-panel on the same XCD L2.
__global__ __launch_bounds__(256, 3) void kan_gemm(
    const int* __restrict__ Apack, const int* __restrict__ Bpack,
    __bf16* __restrict__ iin)
{
    const int tid  = threadIdx.x;
    const int lane = tid & 63;
    const int wave = tid >> 6;
    const int wm   = wave >> 1;
    const int wn   = wave & 1;

    // dispatch-linear id -> chunk per XCD (2000 blocks % 8 == 0, bijective)
    const int p   = blockIdx.y * gridDim.x + blockIdx.x;
    const int lid = (p & 7) * 250 + (p >> 3);
    const int bx  = lid & 3;        // ntile index (N/128 = 4)
    const int by  = lid >> 2;       // mtile index (M/128 = 500)

    const int mtile = by * 128;
    const int ntile = bx * 128;
    const int l31  = lane & 31;
    const int kh   = lane >> 5;
    const int mc0  = by * 4 + wm * 2;
    const int ntb  = bx * 4 + wn * 2;
    const int lanew = (kh * 32 + l31) * 8;    // word offset of this lane's 32B chunk

    f32x16 acc[2][2];
    #pragma unroll
    for (int i = 0; i < 2; ++i)
        #pragma unroll
        for (int j = 0; j < 2; ++j)
            #pragma unroll
            for (int r = 0; r < 16; ++r)
                acc[i][j][r] = 0.0f;

    #pragma unroll 1
    for (int kt = 0; kt < KT_N; ++kt) {
        const int* ab = Apack + ((size_t)(kt * MC_N + mc0)) * 2048 + lanew;
        const int* bb = Bpack + ((size_t)(kt * 16 + ntb)) * 512 + lanew;
        #pragma unroll
        for (int seg = 0; seg < 4; ++seg) {
            i32x8 a0 = *(const i32x8*)(ab + seg * 512);
            i32x8 a1 = *(const i32x8*)(ab + 2048 + seg * 512);   // next mc row-chunk
            i32x8 b0 = *(const i32x8*)(bb + seg * BSEG);
            i32x8 b1 = *(const i32x8*)(bb + seg * BSEG + 512);
            acc[0][0] = __builtin_amdgcn_mfma_scale_f32_32x32x64_f8f6f4(
                a0, b0, acc[0][0], 0, 0, 0, 0x7f7f7f7f, 0, 0x7f7f7f7f);
            acc[0][1] = __builtin_amdgcn_mfma_scale_f32_32x32x64_f8f6f4(
                a0, b1, acc[0][1], 0, 0, 0, 0x7f7f7f7f, 0, 0x7f7f7f7f);
            acc[1][0] = __builtin_amdgcn_mfma_scale_f32_32x32x64_f8f6f4(
                a1, b0, acc[1][0], 0, 0, 0, 0x7f7f7f7f, 0, 0x7f7f7f7f);
            acc[1][1] = __builtin_amdgcn_mfma_scale_f32_32x32x64_f8f6f4(
                a1, b1, acc[1][1], 0, 0, 0, 0x7f7f7f7f, 0, 0x7f7f7f7f);
        }
    }

    // ---- epilogue: 32x32 C/D layout col=lane&31, row=(r&3)+8*(r>>2)+4*(lane>>5) ----
    #pragma unroll
    for (int i = 0; i < 2; ++i) {
        int m0 = mtile + wm * 64 + i * 32 + kh * 4;
        #pragma unroll
        for (int j = 0; j < 2; ++j) {
            int c = ntile + wn * 64 + j * 32 + l31;
            #pragma unroll
            for (int r = 0; r < 16; ++r) {
                int row = m0 + (r & 3) + 8 * (r >> 2);
                iin[(size_t)row * NHID + c] = (__bf16)acc[i][j][r];
            }
        }
    }
}

// ---------------- kernel 4: adaptive-LIF scan, one wave per sample, PF=25 bf16 ----------------
#define PF 25
__global__ __launch_bounds__(64) void kan_scan(
    const __bf16* __restrict__ iin, const float* __restrict__ wrecT,
    const float* __restrict__ w_out, float* __restrict__ out)
{
    const int b    = blockIdx.x;
    const int lane = threadIdx.x;
    const __bf16* basep = iin + (size_t)b * T_ * NHID + lane * 8;
    #define LOADQ(t) (*(const i32x4*)(basep + (size_t)(t) * NHID))

    i32x4 q[PF];
    #pragma unroll
    for (int d = 0; d < PF; ++d) q[d] = LOADQ(d);

    float v1[8], a1[8];
    #pragma unroll
    for (int u = 0; u < 8; ++u) { v1[u] = 0.f; a1[u] = 0.f; }
    unsigned sm = 0;
    int anyprev = 0;
    float v_out = 0.f, acco = 0.f;

    #pragma unroll 1
    for (int t0 = 0; t0 < T_; t0 += PF) {
        #pragma unroll
        for (int j = 0; j < PF; ++j) {
            const int t = t0 + j;
            float cur[8];
            #pragma unroll
            for (int w = 0; w < 4; ++w) {
                int wv = q[j][w];
                cur[2 * w]     = __builtin_bit_cast(float, wv << 16);
                cur[2 * w + 1] = __builtin_bit_cast(float, wv & 0xffff0000);
            }
            if (t + PF < T_) q[j] = LOADQ(t + PF);

            if (anyprev) {           // rare path: recurrent input from prev spikes
                #pragma unroll
                for (int u = 0; u < 8; ++u) {
                    unsigned long long mu = __ballot((sm >> u) & 1u);
                    while (mu) {
                        int jl = __ffsll(mu) - 1; mu &= mu - 1;
                        const float* wr = wrecT + (size_t)(jl * 8 + u) * NHID + lane * 8;
                        f32x4 wa = *(const f32x4*)wr;
                        f32x4 wb = *(const f32x4*)(wr + 4);
                        cur[0] += wa[0]; cur[1] += wa[1]; cur[2] += wa[2]; cur[3] += wa[3];
                        cur[4] += wb[0]; cur[5] += wb[1]; cur[6] += wb[2]; cur[7] += wb[3];
                    }
                }
            }

            unsigned nm = 0;
            #pragma unroll
            for (int u = 0; u < 8; ++u) {
                float sp = ((sm >> u) & 1u) ? 1.0f : 0.0f;
                v1[u] = 0.95f * v1[u] + 0.05f * cur[u] - sp;
                a1[u] = 0.85f * a1[u] + 0.15f * sp;
                if (v1[u] - (1.0f + 0.05f * a1[u]) > 0.0f) nm |= (1u << u);
            }

            unsigned long long anyb = __ballot(nm != 0u);
            float io = 0.0f;
            if (anyb) {              // rare path: readout current from spikes
                #pragma unroll
                for (int u = 0; u < 8; ++u) {
                    unsigned long long mu = __ballot((nm >> u) & 1u);
                    while (mu) {
                        int jl = __ffsll(mu) - 1; mu &= mu - 1;
                        int unit = jl * 8 + u;
                        if (lane < NOUT) io += w_out[(size_t)lane * NHID + unit];
                    }
                }
            }

            v_out = 0.9f * v_out + io;
            float so = (v_out - 1.0f > 0.0f) ? 1.0f : 0.0f;
            v_out -= so;
            acco += v_out;

            sm = nm;
            anyprev = (anyb != 0ull);
        }
    }

    if (lane < NOUT) out[b * NOUT + lane] = acco * (1.0f / 250.0f);
}

// ---------------- launcher ----------------
extern "C" void kernel_launch(void* const* d_in, const int* in_sizes, int n_in,
                              void* d_out, int out_size, void* d_ws, size_t ws_size,
                              hipStream_t stream)
{
    const float* x     = (const float*)d_in[0];
    const float* w_kan = (const float*)d_in[1];
    const float* d1    = (const float*)d_in[2];
    const float* d2    = (const float*)d_in[3];
    const float* d3    = (const float*)d_in[4];
    const float* w_rec = (const float*)d_in[5];
    const float* w_out = (const float*)d_in[6];
    float* out = (float*)d_out;

    char*   ws    = (char*)d_ws;
    __bf16* iin   = (__bf16*)ws;
    int*    Apack = (int*)(ws + APACK_OFF);
    int*    Bpack = (int*)(ws + BPACK_OFF);
    float*  wrecT = (float*)(ws + WRECT_OFF);

    kan_pack<<<dim3((BPACK_WORDS + 255) / 256), 256, 0, stream>>>(
        w_kan, d1, d2, d3, w_rec, Bpack, wrecT);
    kan_packa<<<dim3(MC_N * KT_N), 256, 0, stream>>>(x, Apack);
    kan_gemm<<<dim3(NHID / 128, M_TOT / 128), 256, 0, stream>>>(Apack, Bpack, iin);
    kan_scan<<<dim3(B_), 64, 0, stream>>>(iin, wrecT, w_out, out);
}

// Round 2
// 503.095 us; speedup vs baseline: 1.0665x; 1.0665x over previous
//
#include <hip/hip_runtime.h>
#include <hip/hip_bf16.h>

// ---------------- problem constants ----------------
#define B_    256
#define T_    250
#define NIN   700
#define NHID  512
#define NOUT  20
#define KT_N  11                 // k-tiles of 64 per segment: 704 = 11*64
#define MC_N  2000               // 64000 / 32 row-chunks
#define M_TOT (B_ * T_)          // 64000

typedef float  f32x2  __attribute__((ext_vector_type(2)));
typedef float  f32x4  __attribute__((ext_vector_type(4)));
typedef float  f32x16 __attribute__((ext_vector_type(16)));
typedef int    i32x2  __attribute__((ext_vector_type(2)));
typedef int    i32x4  __attribute__((ext_vector_type(4)));
typedef int    i32x8  __attribute__((ext_vector_type(8)));

// ---------------- workspace layout ----------------
// [0, 65,536,000)   : i_in  (M_TOT x NHID bf16)
// [+, 180,224,000)  : Apack fp8 fragment-major, ALL 4 segs precomputed
//                     word index = ((kt*MC_N + mc)*4 + seg)*512 + t*2
// [+, 1,441,792)    : Bpack fp8 fragment-major (4 segs)
// [+, 1,048,576)    : w_recT (512x512 f32)
// total ~248.3 MB
#define IIN_BYTES   ((size_t)M_TOT * NHID * 2)
#define APACK_OFF   IIN_BYTES
#define APACK_BYTES ((size_t)KT_N * MC_N * 4 * 2048)
#define BPACK_OFF   (APACK_OFF + APACK_BYTES)
#define BPACK_BYTES ((size_t)4 * KT_N * 16 * 64 * 32)
#define BPACK_WORDS (BPACK_BYTES / 4)                  // 360,448
#define WRECT_OFF   (BPACK_OFF + BPACK_BYTES)
#define BSEG        (KT_N * 16 * 512)                  // 90,112 words per B seg

// ---------------- kernel 1: pack B to fp8 fragment-major + transpose w_rec ----------------
__global__ __launch_bounds__(256) void kan_pack(
    const float* __restrict__ w_kan, const float* __restrict__ d1,
    const float* __restrict__ d2,    const float* __restrict__ d3,
    const float* __restrict__ w_rec,
    int* __restrict__ BpackW, float* __restrict__ wrecT)
{
    int idx = blockIdx.x * 256 + threadIdx.x;
    if (idx < (int)BPACK_WORDS) {
        int w   = idx;
        int c   = w >> 3;                  // 32-byte chunk index
        int jj  = (w & 7) * 4;             // byte offset within chunk
        int ln  = c & 31;
        int kh  = (c >> 5) & 1;
        int nt  = (c >> 6) & 15;
        int ks  = c >> 10;                 // seg*11 + kt
        int kt  = ks % 11;
        int seg = ks / 11;
        int n   = nt * 32 + ln;
        int kb  = kt * 64 + kh * 32 + jj;
        const float* wp = (seg == 0) ? w_kan : (seg == 1) ? d1 : (seg == 2) ? d2 : d3;
        float f0 = (kb + 0 < NIN) ? wp[(size_t)n * NIN + kb + 0] : 0.0f;
        float f1 = (kb + 1 < NIN) ? wp[(size_t)n * NIN + kb + 1] : 0.0f;
        float f2 = (kb + 2 < NIN) ? wp[(size_t)n * NIN + kb + 2] : 0.0f;
        float f3 = (kb + 3 < NIN) ? wp[(size_t)n * NIN + kb + 3] : 0.0f;
        int u = __builtin_amdgcn_cvt_pk_fp8_f32(f0, f1, 0, false);
        u     = __builtin_amdgcn_cvt_pk_fp8_f32(f2, f3, u, true);
        BpackW[w] = u;
    }
    if (idx < NHID * NHID) {
        int h  = idx & 511;
        int hp = idx >> 9;
        wrecT[(size_t)hp * NHID + h] = w_rec[(size_t)h * NHID + hp];
    }
}

// ---------------- kernel 2: pack x AND t1/t2/t3 to fp8 A-fragment-major ----------------
__global__ __launch_bounds__(256) void kan_packa(
    const float* __restrict__ x, int* __restrict__ Apack)
{
    int blk = blockIdx.x;          // mc*11 + kt
    int kt  = blk % KT_N;
    int mc  = blk / KT_N;
    int t   = threadIdx.x;
    int q   = t & 3;
    int r   = (t >> 2) & 31;
    int kh  = t >> 7;
    int k0  = kt * 64 + kh * 32 + q * 8;      // max 696
    const float* xr = x + (size_t)(mc * 32 + r) * NIN + k0;
    f32x4 v0 = *(const f32x4*)xr;             // always in-range (k0+3 <= 699)
    f32x4 v1 = {0.f, 0.f, 0.f, 0.f};
    if (k0 + 7 < NIN) v1 = *(const f32x4*)(xr + 4);

    float e[8] = {v0[0], v0[1], v0[2], v0[3], v1[0], v1[1], v1[2], v1[3]};
    float p1[8], p2[8], p3[8];
    #pragma unroll
    for (int u = 0; u < 8; ++u) {
        p1[u] = fminf(fabsf(e[u]), 1.0f);     // t1 = clip(|x|,0,1)
        p2[u] = p1[u] * p1[u];
        p3[u] = p2[u] * p1[u];
    }

    int* base = Apack + ((size_t)(kt * MC_N + mc)) * 2048 + t * 2;
    // seg 0: raw x
    {
        int u0 = __builtin_amdgcn_cvt_pk_fp8_f32(e[0], e[1], 0, false);
        u0     = __builtin_amdgcn_cvt_pk_fp8_f32(e[2], e[3], u0, true);
        int u1 = __builtin_amdgcn_cvt_pk_fp8_f32(e[4], e[5], 0, false);
        u1     = __builtin_amdgcn_cvt_pk_fp8_f32(e[6], e[7], u1, true);
        *(i32x2*)base = i32x2{u0, u1};
    }
    // seg 1: t1
    {
        int u0 = __builtin_amdgcn_cvt_pk_fp8_f32(p1[0], p1[1], 0, false);
        u0     = __builtin_amdgcn_cvt_pk_fp8_f32(p1[2], p1[3], u0, true);
        int u1 = __builtin_amdgcn_cvt_pk_fp8_f32(p1[4], p1[5], 0, false);
        u1     = __builtin_amdgcn_cvt_pk_fp8_f32(p1[6], p1[7], u1, true);
        *(i32x2*)(base + 512) = i32x2{u0, u1};
    }
    // seg 2: t1^2
    {
        int u0 = __builtin_amdgcn_cvt_pk_fp8_f32(p2[0], p2[1], 0, false);
        u0     = __builtin_amdgcn_cvt_pk_fp8_f32(p2[2], p2[3], u0, true);
        int u1 = __builtin_amdgcn_cvt_pk_fp8_f32(p2[4], p2[5], 0, false);
        u1     = __builtin_amdgcn_cvt_pk_fp8_f32(p2[6], p2[7], u1, true);
        *(i32x2*)(base + 1024) = i32x2{u0, u1};
    }
    // seg 3: t1^3
    {
        int u0 = __builtin_amdgcn_cvt_pk_fp8_f32(p3[0], p3[1], 0, false);
        u0     = __builtin_amdgcn_cvt_pk_fp8_f32(p3[2], p3[3], u0, true);
        int u1 = __builtin_amdgcn_cvt_pk_fp8_f32(p3[4], p3[5], 0, false);
        u1     = __builtin_amdgcn_cvt_pk_fp8_f32(p3[6], p3[7], u1, true);
        *(i32x2*)(base + 1536) = i32x2{u0, u1};
    }
}

// ---------------- kernel 3: barrier-free fp8 GEMM, forced-MLP inner loop ----------------
// R1 post-mortem: compiler minimized registers (VGPR=60) -> ~3 loads in flight ->
// latency-bound (MfmaUtil 19%, VALU 6%, HBM 11%). Fix: stage the entire k-tile
// (16 x i32x8 = 32 dwordx4 loads) into NAMED registers, pin with sched_barrier(0)
// so loads cannot sink into the MFMA block. Seg0 operands load first so in-order
// vmcnt retirement lets MFMAs start as early as possible.
__global__ __launch_bounds__(256, 2) void kan_gemm(
    const int* __restrict__ Apack, const int* __restrict__ Bpack,
    __bf16* __restrict__ iin)
{
    const int tid  = threadIdx.x;
    const int lane = tid & 63;
    const int wave = tid >> 6;
    const int wm   = wave >> 1;
    const int wn   = wave & 1;

    // dispatch-linear id -> chunk per XCD (2000 blocks % 8 == 0, bijective)
    const int p   = blockIdx.y * gridDim.x + blockIdx.x;
    const int lid = (p & 7) * 250 + (p >> 3);
    const int bx  = lid & 3;        // ntile index (N/128 = 4)
    const int by  = lid >> 2;       // mtile index (M/128 = 500)

    const int mtile = by * 128;
    const int ntile = bx * 128;
    const int l31  = lane & 31;
    const int kh   = lane >> 5;
    const int mc0  = by * 4 + wm * 2;
    const int ntb  = bx * 4 + wn * 2;
    const int lanew = (kh * 32 + l31) * 8;    // word offset of this lane's 32B chunk

    f32x16 acc[2][2];
    #pragma unroll
    for (int i = 0; i < 2; ++i)
        #pragma unroll
        for (int j = 0; j < 2; ++j)
            #pragma unroll
            for (int r = 0; r < 16; ++r)
                acc[i][j][r] = 0.0f;

    #pragma unroll 1
    for (int kt = 0; kt < KT_N; ++kt) {
        const int* ab = Apack + ((size_t)(kt * MC_N + mc0)) * 2048 + lanew;
        const int* bb = Bpack + ((size_t)(kt * 16 + ntb)) * 512 + lanew;

        // ---- phase 1: issue ALL 32 dwordx4 loads (seg0 first) ----
        i32x8 A00 = *(const i32x8*)(ab);                     // seg0, mc0
        i32x8 A10 = *(const i32x8*)(ab + 2048);              // seg0, mc0+1
        i32x8 B00 = *(const i32x8*)(bb);
        i32x8 B10 = *(const i32x8*)(bb + 512);
        i32x8 A01 = *(const i32x8*)(ab + 512);               // seg1
        i32x8 A11 = *(const i32x8*)(ab + 2048 + 512);
        i32x8 B01 = *(const i32x8*)(bb + BSEG);
        i32x8 B11 = *(const i32x8*)(bb + BSEG + 512);
        i32x8 A02 = *(const i32x8*)(ab + 1024);              // seg2
        i32x8 A12 = *(const i32x8*)(ab + 2048 + 1024);
        i32x8 B02 = *(const i32x8*)(bb + 2 * BSEG);
        i32x8 B12 = *(const i32x8*)(bb + 2 * BSEG + 512);
        i32x8 A03 = *(const i32x8*)(ab + 1536);              // seg3
        i32x8 A13 = *(const i32x8*)(ab + 2048 + 1536);
        i32x8 B03 = *(const i32x8*)(bb + 3 * BSEG);
        i32x8 B13 = *(const i32x8*)(bb + 3 * BSEG + 512);

        __builtin_amdgcn_sched_barrier(0);   // loads stay above, MFMAs below

        // ---- phase 2: 16 MFMAs, consume in load order ----
        acc[0][0] = __builtin_amdgcn_mfma_scale_f32_32x32x64_f8f6f4(
            A00, B00, acc[0][0], 0, 0, 0, 0x7f7f7f7f, 0, 0x7f7f7f7f);
        acc[0][1] = __builtin_amdgcn_mfma_scale_f32_32x32x64_f8f6f4(
            A00, B10, acc[0][1], 0, 0, 0, 0x7f7f7f7f, 0, 0x7f7f7f7f);
        acc[1][0] = __builtin_amdgcn_mfma_scale_f32_32x32x64_f8f6f4(
            A10, B00, acc[1][0], 0, 0, 0, 0x7f7f7f7f, 0, 0x7f7f7f7f);
        acc[1][1] = __builtin_amdgcn_mfma_scale_f32_32x32x64_f8f6f4(
            A10, B10, acc[1][1], 0, 0, 0, 0x7f7f7f7f, 0, 0x7f7f7f7f);

        acc[0][0] = __builtin_amdgcn_mfma_scale_f32_32x32x64_f8f6f4(
            A01, B01, acc[0][0], 0, 0, 0, 0x7f7f7f7f, 0, 0x7f7f7f7f);
        acc[0][1] = __builtin_amdgcn_mfma_scale_f32_32x32x64_f8f6f4(
            A01, B11, acc[0][1], 0, 0, 0, 0x7f7f7f7f, 0, 0x7f7f7f7f);
        acc[1][0] = __builtin_amdgcn_mfma_scale_f32_32x32x64_f8f6f4(
            A11, B01, acc[1][0], 0, 0, 0, 0x7f7f7f7f, 0, 0x7f7f7f7f);
        acc[1][1] = __builtin_amdgcn_mfma_scale_f32_32x32x64_f8f6f4(
            A11, B11, acc[1][1], 0, 0, 0, 0x7f7f7f7f, 0, 0x7f7f7f7f);

        acc[0][0] = __builtin_amdgcn_mfma_scale_f32_32x32x64_f8f6f4(
            A02, B02, acc[0][0], 0, 0, 0, 0x7f7f7f7f, 0, 0x7f7f7f7f);
        acc[0][1] = __builtin_amdgcn_mfma_scale_f32_32x32x64_f8f6f4(
            A02, B12, acc[0][1], 0, 0, 0, 0x7f7f7f7f, 0, 0x7f7f7f7f);
        acc[1][0] = __builtin_amdgcn_mfma_scale_f32_32x32x64_f8f6f4(
            A12, B02, acc[1][0], 0, 0, 0, 0x7f7f7f7f, 0, 0x7f7f7f7f);
        acc[1][1] = __builtin_amdgcn_mfma_scale_f32_32x32x64_f8f6f4(
            A12, B12, acc[1][1], 0, 0, 0, 0x7f7f7f7f, 0, 0x7f7f7f7f);

        acc[0][0] = __builtin_amdgcn_mfma_scale_f32_32x32x64_f8f6f4(
            A03, B03, acc[0][0], 0, 0, 0, 0x7f7f7f7f, 0, 0x7f7f7f7f);
        acc[0][1] = __builtin_amdgcn_mfma_scale_f32_32x32x64_f8f6f4(
            A03, B13, acc[0][1], 0, 0, 0, 0x7f7f7f7f, 0, 0x7f7f7f7f);
        acc[1][0] = __builtin_amdgcn_mfma_scale_f32_32x32x64_f8f6f4(
            A13, B03, acc[1][0], 0, 0, 0, 0x7f7f7f7f, 0, 0x7f7f7f7f);
        acc[1][1] = __builtin_amdgcn_mfma_scale_f32_32x32x64_f8f6f4(
            A13, B13, acc[1][1], 0, 0, 0, 0x7f7f7f7f, 0, 0x7f7f7f7f);
    }

    // ---- epilogue: 32x32 C/D layout col=lane&31, row=(r&3)+8*(r>>2)+4*(lane>>5) ----
    #pragma unroll
    for (int i = 0; i < 2; ++i) {
        int m0 = mtile + wm * 64 + i * 32 + kh * 4;
        #pragma unroll
        for (int j = 0; j < 2; ++j) {
            int c = ntile + wn * 64 + j * 32 + l31;
            #pragma unroll
            for (int r = 0; r < 16; ++r) {
                int row = m0 + (r & 3) + 8 * (r >> 2);
                iin[(size_t)row * NHID + c] = (__bf16)acc[i][j][r];
            }
        }
    }
}

// ---------------- kernel 4: adaptive-LIF scan, one wave per sample, PF=25 bf16 ----------------
#define PF 25
__global__ __launch_bounds__(64) void kan_scan(
    const __bf16* __restrict__ iin, const float* __restrict__ wrecT,
    const float* __restrict__ w_out, float* __restrict__ out)
{
    const int b    = blockIdx.x;
    const int lane = threadIdx.x;
    const __bf16* basep = iin + (size_t)b * T_ * NHID + lane * 8;
    #define LOADQ(t) (*(const i32x4*)(basep + (size_t)(t) * NHID))

    i32x4 q[PF];
    #pragma unroll
    for (int d = 0; d < PF; ++d) q[d] = LOADQ(d);

    float v1[8], a1[8];
    #pragma unroll
    for (int u = 0; u < 8; ++u) { v1[u] = 0.f; a1[u] = 0.f; }
    unsigned sm = 0;
    int anyprev = 0;
    float v_out = 0.f, acco = 0.f;

    #pragma unroll 1
    for (int t0 = 0; t0 < T_; t0 += PF) {
        #pragma unroll
        for (int j = 0; j < PF; ++j) {
            const int t = t0 + j;
            float cur[8];
            #pragma unroll
            for (int w = 0; w < 4; ++w) {
                int wv = q[j][w];
                cur[2 * w]     = __builtin_bit_cast(float, wv << 16);
                cur[2 * w + 1] = __builtin_bit_cast(float, wv & 0xffff0000);
            }
            if (t + PF < T_) q[j] = LOADQ(t + PF);

            if (anyprev) {           // rare path: recurrent input from prev spikes
                #pragma unroll
                for (int u = 0; u < 8; ++u) {
                    unsigned long long mu = __ballot((sm >> u) & 1u);
                    while (mu) {
                        int jl = __ffsll(mu) - 1; mu &= mu - 1;
                        const float* wr = wrecT + (size_t)(jl * 8 + u) * NHID + lane * 8;
                        f32x4 wa = *(const f32x4*)wr;
                        f32x4 wb = *(const f32x4*)(wr + 4);
                        cur[0] += wa[0]; cur[1] += wa[1]; cur[2] += wa[2]; cur[3] += wa[3];
                        cur[4] += wb[0]; cur[5] += wb[1]; cur[6] += wb[2]; cur[7] += wb[3];
                    }
                }
            }

            unsigned nm = 0;
            #pragma unroll
            for (int u = 0; u < 8; ++u) {
                float sp = ((sm >> u) & 1u) ? 1.0f : 0.0f;
                v1[u] = 0.95f * v1[u] + 0.05f * cur[u] - sp;
                a1[u] = 0.85f * a1[u] + 0.15f * sp;
                if (v1[u] - (1.0f + 0.05f * a1[u]) > 0.0f) nm |= (1u << u);
            }

            unsigned long long anyb = __ballot(nm != 0u);
            float io = 0.0f;
            if (anyb) {              // rare path: readout current from spikes
                #pragma unroll
                for (int u = 0; u < 8; ++u) {
                    unsigned long long mu = __ballot((nm >> u) & 1u);
                    while (mu) {
                        int jl = __ffsll(mu) - 1; mu &= mu - 1;
                        int unit = jl * 8 + u;
                        if (lane < NOUT) io += w_out[(size_t)lane * NHID + unit];
                    }
                }
            }

            v_out = 0.9f * v_out + io;
            float so = (v_out - 1.0f > 0.0f) ? 1.0f : 0.0f;
            v_out -= so;
            acco += v_out;

            sm = nm;
            anyprev = (anyb != 0ull);
        }
    }

    if (lane < NOUT) out[b * NOUT + lane] = acco * (1.0f / 250.0f);
}

// ---------------- launcher ----------------
extern "C" void kernel_launch(void* const* d_in, const int* in_sizes, int n_in,
                              void* d_out, int out_size, void* d_ws, size_t ws_size,
                              hipStream_t stream)
{
    const float* x     = (const float*)d_in[0];
    const float* w_kan = (const float*)d_in[1];
    const float* d1    = (const float*)d_in[2];
    const float* d2    = (const float*)d_in[3];
    const float* d3    = (const float*)d_in[4];
    const float* w_rec = (const float*)d_in[5];
    const float* w_out = (const float*)d_in[6];
    float* out = (float*)d_out;

    char*   ws    = (char*)d_ws;
    __bf16* iin   = (__bf16*)ws;
    int*    Apack = (int*)(ws + APACK_OFF);
    int*    Bpack = (int*)(ws + BPACK_OFF);
    float*  wrecT = (float*)(ws + WRECT_OFF);

    kan_pack<<<dim3((BPACK_WORDS + 255) / 256), 256, 0, stream>>>(
        w_kan, d1, d2, d3, w_rec, Bpack, wrecT);
    kan_packa<<<dim3(MC_N * KT_N), 256, 0, stream>>>(x, Apack);
    kan_gemm<<<dim3(NHID / 128, M_TOT / 128), 256, 0, stream>>>(Apack, Bpack, iin);
    kan_scan<<<dim3(B_), 64, 0, stream>>>(iin, wrecT, w_out, out);
}

// Round 3
// 480.197 us; speedup vs baseline: 1.1173x; 1.0477x over previous
//
#include <hip/hip_runtime.h>
#include <hip/hip_bf16.h>

// ---------------- problem constants ----------------
#define B_    256
#define T_    250
#define NIN   700
#define NHID  512
#define NOUT  20
#define KT_N  11                 // k-tiles of 64 per segment: 704 = 11*64
#define MC_N  2000               // 64000 / 32 row-chunks
#define M_TOT (B_ * T_)          // 64000

typedef float  f32x2  __attribute__((ext_vector_type(2)));
typedef float  f32x4  __attribute__((ext_vector_type(4)));
typedef float  f32x16 __attribute__((ext_vector_type(16)));
typedef int    i32x2  __attribute__((ext_vector_type(2)));
typedef int    i32x4  __attribute__((ext_vector_type(4)));
typedef int    i32x8  __attribute__((ext_vector_type(8)));

// ---------------- workspace layout ----------------
// [0, 65,536,000)   : i_in  (M_TOT x NHID bf16)
// [+, 180,224,000)  : Apack fp8 fragment-major, ALL 4 segs precomputed
//                     word index = (kt*MC_N + mc)*2048 + seg*512 + h*256 + lane*4 + i
//                     (within-block order [seg][half16B][lane][4 words] so that
//                      global_load_lds linear dest == ds_read lane-stride-16B order)
// [+, 1,441,792)    : Bpack fp8 fragment-major (4 segs)
// [+, 1,048,576)    : w_recT (512x512 f32)
// total ~248.3 MB
#define IIN_BYTES   ((size_t)M_TOT * NHID * 2)
#define APACK_OFF   IIN_BYTES
#define APACK_BYTES ((size_t)KT_N * MC_N * 4 * 2048)
#define BPACK_OFF   (APACK_OFF + APACK_BYTES)
#define BPACK_BYTES ((size_t)4 * KT_N * 16 * 64 * 32)
#define BPACK_WORDS (BPACK_BYTES / 4)                  // 360,448
#define WRECT_OFF   (BPACK_OFF + BPACK_BYTES)
#define BSEG        (KT_N * 16 * 512)                  // 90,112 words per B seg

// async global->LDS: 16B per lane, LDS dest = uniform base + lane*16
__device__ __forceinline__ void gload_lds16(const int* g, int* l) {
    __builtin_amdgcn_global_load_lds(
        (const __attribute__((address_space(1))) void*)g,
        (__attribute__((address_space(3))) void*)l,
        16, 0, 0);
}

// ---------------- kernel 1: pack B to fp8 fragment-major + transpose w_rec ----------------
__global__ __launch_bounds__(256) void kan_pack(
    const float* __restrict__ w_kan, const float* __restrict__ d1,
    const float* __restrict__ d2,    const float* __restrict__ d3,
    const float* __restrict__ w_rec,
    int* __restrict__ BpackW, float* __restrict__ wrecT)
{
    int idx = blockIdx.x * 256 + threadIdx.x;
    if (idx < (int)BPACK_WORDS) {
        int w   = idx;
        int c   = w >> 3;                  // 32-byte chunk index
        int jj  = (w & 7) * 4;             // byte offset within chunk
        int ln  = c & 31;
        int kh  = (c >> 5) & 1;
        int nt  = (c >> 6) & 15;
        int ks  = c >> 10;                 // seg*11 + kt
        int kt  = ks % 11;
        int seg = ks / 11;
        int n   = nt * 32 + ln;
        int kb  = kt * 64 + kh * 32 + jj;
        const float* wp = (seg == 0) ? w_kan : (seg == 1) ? d1 : (seg == 2) ? d2 : d3;
        float f0 = (kb + 0 < NIN) ? wp[(size_t)n * NIN + kb + 0] : 0.0f;
        float f1 = (kb + 1 < NIN) ? wp[(size_t)n * NIN + kb + 1] : 0.0f;
        float f2 = (kb + 2 < NIN) ? wp[(size_t)n * NIN + kb + 2] : 0.0f;
        float f3 = (kb + 3 < NIN) ? wp[(size_t)n * NIN + kb + 3] : 0.0f;
        int u = __builtin_amdgcn_cvt_pk_fp8_f32(f0, f1, 0, false);
        u     = __builtin_amdgcn_cvt_pk_fp8_f32(f2, f3, u, true);
        BpackW[w] = u;
    }
    if (idx < NHID * NHID) {
        int h  = idx & 511;
        int hp = idx >> 9;
        wrecT[(size_t)hp * NHID + h] = w_rec[(size_t)h * NHID + hp];
    }
}

// ---------------- kernel 2: pack x AND t1/t2/t3 to fp8 A-fragment-major ----------------
// Within-seg-block word offset for thread (kh,r,q), pair (q&1):
//   w0 = (q>>1)*256 + kh*128 + r*4 + (q&1)*2     ([half][lane][16B] order)
__global__ __launch_bounds__(256) void kan_packa(
    const float* __restrict__ x, int* __restrict__ Apack)
{
    int blk = blockIdx.x;          // mc*11 + kt
    int kt  = blk % KT_N;
    int mc  = blk / KT_N;
    int t   = threadIdx.x;
    int q   = t & 3;
    int r   = (t >> 2) & 31;
    int kh  = t >> 7;
    int k0  = kt * 64 + kh * 32 + q * 8;      // max 696
    const float* xr = x + (size_t)(mc * 32 + r) * NIN + k0;
    f32x4 v0 = *(const f32x4*)xr;             // always in-range (k0+3 <= 699)
    f32x4 v1 = {0.f, 0.f, 0.f, 0.f};
    if (k0 + 7 < NIN) v1 = *(const f32x4*)(xr + 4);

    float e[8] = {v0[0], v0[1], v0[2], v0[3], v1[0], v1[1], v1[2], v1[3]};
    float p1[8], p2[8], p3[8];
    #pragma unroll
    for (int u = 0; u < 8; ++u) {
        p1[u] = fminf(fabsf(e[u]), 1.0f);     // t1 = clip(|x|,0,1)
        p2[u] = p1[u] * p1[u];
        p3[u] = p2[u] * p1[u];
    }

    int* segbase = Apack + ((size_t)(kt * MC_N + mc)) * 2048;
    int  w0 = (q >> 1) * 256 + kh * 128 + r * 4 + (q & 1) * 2;
    // seg 0: raw x
    {
        int u0 = __builtin_amdgcn_cvt_pk_fp8_f32(e[0], e[1], 0, false);
        u0     = __builtin_amdgcn_cvt_pk_fp8_f32(e[2], e[3], u0, true);
        int u1 = __builtin_amdgcn_cvt_pk_fp8_f32(e[4], e[5], 0, false);
        u1     = __builtin_amdgcn_cvt_pk_fp8_f32(e[6], e[7], u1, true);
        *(i32x2*)(segbase + w0) = i32x2{u0, u1};
    }
    // seg 1: t1
    {
        int u0 = __builtin_amdgcn_cvt_pk_fp8_f32(p1[0], p1[1], 0, false);
        u0     = __builtin_amdgcn_cvt_pk_fp8_f32(p1[2], p1[3], u0, true);
        int u1 = __builtin_amdgcn_cvt_pk_fp8_f32(p1[4], p1[5], 0, false);
        u1     = __builtin_amdgcn_cvt_pk_fp8_f32(p1[6], p1[7], u1, true);
        *(i32x2*)(segbase + 512 + w0) = i32x2{u0, u1};
    }
    // seg 2: t1^2
    {
        int u0 = __builtin_amdgcn_cvt_pk_fp8_f32(p2[0], p2[1], 0, false);
        u0     = __builtin_amdgcn_cvt_pk_fp8_f32(p2[2], p2[3], u0, true);
        int u1 = __builtin_amdgcn_cvt_pk_fp8_f32(p2[4], p2[5], 0, false);
        u1     = __builtin_amdgcn_cvt_pk_fp8_f32(p2[6], p2[7], u1, true);
        *(i32x2*)(segbase + 1024 + w0) = i32x2{u0, u1};
    }
    // seg 3: t1^3
    {
        int u0 = __builtin_amdgcn_cvt_pk_fp8_f32(p3[0], p3[1], 0, false);
        u0     = __builtin_amdgcn_cvt_pk_fp8_f32(p3[2], p3[3], u0, true);
        int u1 = __builtin_amdgcn_cvt_pk_fp8_f32(p3[4], p3[5], 0, false);
        u1     = __builtin_amdgcn_cvt_pk_fp8_f32(p3[6], p3[7], u1, true);
        *(i32x2*)(segbase + 1536 + w0) = i32x2{u0, u1};
    }
}

// ---------------- kernel 3: fp8 GEMM, 2-phase LDS pipeline (T3 minimum) ----------------
// R2 post-mortem: register-resident prefetch can't be forced (VGPR=104, MfmaUtil 23%).
// Now: A staged via global_load_lds (no VGPR dest -> full MLP), double-buffered 2x32KB.
// Per kt: B reg-loads (L2-hot) -> stage(kt+1) -> ds_read A(kt) -> 16 MFMA -> syncthreads
// (the sync's vmcnt(0) is the once-per-tile drain; stage had a full tile of MFMA to hide).
__global__ __launch_bounds__(256, 2) void kan_gemm(
    const int* __restrict__ Apack, const int* __restrict__ Bpack,
    __bf16* __restrict__ iin)
{
    __shared__ int lds[2][8192];              // 2 x 32 KB A tile

    const int tid  = threadIdx.x;
    const int lane = tid & 63;
    const int wave = tid >> 6;
    const int wm   = wave >> 1;
    const int wn   = wave & 1;

    // dispatch-linear id -> chunk per XCD (2000 blocks % 8 == 0, bijective)
    const int p   = blockIdx.y * gridDim.x + blockIdx.x;
    const int lid = (p & 7) * 250 + (p >> 3);
    const int bx  = lid & 3;        // ntile index (N/128 = 4)
    const int by  = lid >> 2;       // mtile index (M/128 = 500)

    const int mtile = by * 128;
    const int ntile = bx * 128;
    const int l31  = lane & 31;
    const int kh   = lane >> 5;
    const int ntb  = bx * 4 + wn * 2;
    const int lanew = (kh * 32 + l31) * 8;    // B word offset (unchanged layout)
    const int by4  = by * 4;
    const int lw   = lane * 4;                // A LDS word offset for this lane

    f32x16 acc[2][2];
    #pragma unroll
    for (int i = 0; i < 2; ++i)
        #pragma unroll
        for (int j = 0; j < 2; ++j)
            #pragma unroll
            for (int r = 0; r < 16; ++r)
                acc[i][j][r] = 0.0f;

    // ---- prologue: stage kt=0 into buf 0 (wave w stages row-chunk w, all 4 segs) ----
    {
        const int* srcb = Apack + ((size_t)(by4 + wave)) * 2048 + lw;
        int* dstb = &lds[0][wave * 2048];
        #pragma unroll
        for (int s = 0; s < 4; ++s) {
            gload_lds16(srcb + s * 512,       dstb + s * 512);
            gload_lds16(srcb + s * 512 + 256, dstb + s * 512 + 256);
        }
    }
    __syncthreads();

    int buf = 0;
    #pragma unroll 1
    for (int kt = 0; kt < KT_N; ++kt) {
        // ---- B register loads FIRST (older than stage -> compiler waits vmcnt(8)) ----
        const int* bb = Bpack + ((size_t)(kt * 16 + ntb)) * 512 + lanew;
        i32x8 B00 = *(const i32x8*)(bb);
        i32x8 B10 = *(const i32x8*)(bb + 512);
        i32x8 B01 = *(const i32x8*)(bb + BSEG);
        i32x8 B11 = *(const i32x8*)(bb + BSEG + 512);
        i32x8 B02 = *(const i32x8*)(bb + 2 * BSEG);
        i32x8 B12 = *(const i32x8*)(bb + 2 * BSEG + 512);
        i32x8 B03 = *(const i32x8*)(bb + 3 * BSEG);
        i32x8 B13 = *(const i32x8*)(bb + 3 * BSEG + 512);
        __builtin_amdgcn_sched_barrier(0);

        // ---- stage next A tile into buf^1 ----
        if (kt + 1 < KT_N) {
            const int* srcb = Apack + ((size_t)((kt + 1) * MC_N + by4 + wave)) * 2048 + lw;
            int* dstb = &lds[buf ^ 1][wave * 2048];
            #pragma unroll
            for (int s = 0; s < 4; ++s) {
                gload_lds16(srcb + s * 512,       dstb + s * 512);
                gload_lds16(srcb + s * 512 + 256, dstb + s * 512 + 256);
            }
        }
        __builtin_amdgcn_sched_barrier(0);

        // ---- ds_read A fragments for kt (lane-stride 16B: conflict-free) ----
        i32x8 A0[4], A1[4];
        {
            const int fb0 = (wm * 2) * 2048;
            const int fb1 = (wm * 2 + 1) * 2048;
            #pragma unroll
            for (int s = 0; s < 4; ++s) {
                i32x4 lo = *(const i32x4*)&lds[buf][fb0 + s * 512 + lw];
                i32x4 hi = *(const i32x4*)&lds[buf][fb0 + s * 512 + 256 + lw];
                A0[s] = i32x8{lo[0], lo[1], lo[2], lo[3], hi[0], hi[1], hi[2], hi[3]};
                i32x4 lo1 = *(const i32x4*)&lds[buf][fb1 + s * 512 + lw];
                i32x4 hi1 = *(const i32x4*)&lds[buf][fb1 + s * 512 + 256 + lw];
                A1[s] = i32x8{lo1[0], lo1[1], lo1[2], lo1[3], hi1[0], hi1[1], hi1[2], hi1[3]};
            }
        }

        // ---- 16 MFMAs ----
        acc[0][0] = __builtin_amdgcn_mfma_scale_f32_32x32x64_f8f6f4(
            A0[0], B00, acc[0][0], 0, 0, 0, 0x7f7f7f7f, 0, 0x7f7f7f7f);
        acc[0][1] = __builtin_amdgcn_mfma_scale_f32_32x32x64_f8f6f4(
            A0[0], B10, acc[0][1], 0, 0, 0, 0x7f7f7f7f, 0, 0x7f7f7f7f);
        acc[1][0] = __builtin_amdgcn_mfma_scale_f32_32x32x64_f8f6f4(
            A1[0], B00, acc[1][0], 0, 0, 0, 0x7f7f7f7f, 0, 0x7f7f7f7f);
        acc[1][1] = __builtin_amdgcn_mfma_scale_f32_32x32x64_f8f6f4(
            A1[0], B10, acc[1][1], 0, 0, 0, 0x7f7f7f7f, 0, 0x7f7f7f7f);

        acc[0][0] = __builtin_amdgcn_mfma_scale_f32_32x32x64_f8f6f4(
            A0[1], B01, acc[0][0], 0, 0, 0, 0x7f7f7f7f, 0, 0x7f7f7f7f);
        acc[0][1] = __builtin_amdgcn_mfma_scale_f32_32x32x64_f8f6f4(
            A0[1], B11, acc[0][1], 0, 0, 0, 0x7f7f7f7f, 0, 0x7f7f7f7f);
        acc[1][0] = __builtin_amdgcn_mfma_scale_f32_32x32x64_f8f6f4(
            A1[1], B01, acc[1][0], 0, 0, 0, 0x7f7f7f7f, 0, 0x7f7f7f7f);
        acc[1][1] = __builtin_amdgcn_mfma_scale_f32_32x32x64_f8f6f4(
            A1[1], B11, acc[1][1], 0, 0, 0, 0x7f7f7f7f, 0, 0x7f7f7f7f);

        acc[0][0] = __builtin_amdgcn_mfma_scale_f32_32x32x64_f8f6f4(
            A0[2], B02, acc[0][0], 0, 0, 0, 0x7f7f7f7f, 0, 0x7f7f7f7f);
        acc[0][1] = __builtin_amdgcn_mfma_scale_f32_32x32x64_f8f6f4(
            A0[2], B12, acc[0][1], 0, 0, 0, 0x7f7f7f7f, 0, 0x7f7f7f7f);
        acc[1][0] = __builtin_amdgcn_mfma_scale_f32_32x32x64_f8f6f4(
            A1[2], B02, acc[1][0], 0, 0, 0, 0x7f7f7f7f, 0, 0x7f7f7f7f);
        acc[1][1] = __builtin_amdgcn_mfma_scale_f32_32x32x64_f8f6f4(
            A1[2], B12, acc[1][1], 0, 0, 0, 0x7f7f7f7f, 0, 0x7f7f7f7f);

        acc[0][0] = __builtin_amdgcn_mfma_scale_f32_32x32x64_f8f6f4(
            A0[3], B03, acc[0][0], 0, 0, 0, 0x7f7f7f7f, 0, 0x7f7f7f7f);
        acc[0][1] = __builtin_amdgcn_mfma_scale_f32_32x32x64_f8f6f4(
            A0[3], B13, acc[0][1], 0, 0, 0, 0x7f7f7f7f, 0, 0x7f7f7f7f);
        acc[1][0] = __builtin_amdgcn_mfma_scale_f32_32x32x64_f8f6f4(
            A1[3], B03, acc[1][0], 0, 0, 0, 0x7f7f7f7f, 0, 0x7f7f7f7f);
        acc[1][1] = __builtin_amdgcn_mfma_scale_f32_32x32x64_f8f6f4(
            A1[3], B13, acc[1][1], 0, 0, 0, 0x7f7f7f7f, 0, 0x7f7f7f7f);

        __syncthreads();          // vmcnt(0): stage(kt+1) landed; flip buffers
        buf ^= 1;
    }

    // ---- epilogue: 32x32 C/D layout col=lane&31, row=(r&3)+8*(r>>2)+4*(lane>>5) ----
    #pragma unroll
    for (int i = 0; i < 2; ++i) {
        int m0 = mtile + wm * 64 + i * 32 + kh * 4;
        #pragma unroll
        for (int j = 0; j < 2; ++j) {
            int c = ntile + wn * 64 + j * 32 + l31;
            #pragma unroll
            for (int r = 0; r < 16; ++r) {
                int row = m0 + (r & 3) + 8 * (r >> 2);
                iin[(size_t)row * NHID + c] = (__bf16)acc[i][j][r];
            }
        }
    }
}

// ---------------- kernel 4: adaptive-LIF scan, one wave per sample, PF=25 bf16 ----------------
#define PF 25
__global__ __launch_bounds__(64) void kan_scan(
    const __bf16* __restrict__ iin, const float* __restrict__ wrecT,
    const float* __restrict__ w_out, float* __restrict__ out)
{
    const int b    = blockIdx.x;
    const int lane = threadIdx.x;
    const __bf16* basep = iin + (size_t)b * T_ * NHID + lane * 8;
    #define LOADQ(t) (*(const i32x4*)(basep + (size_t)(t) * NHID))

    i32x4 q[PF];
    #pragma unroll
    for (int d = 0; d < PF; ++d) q[d] = LOADQ(d);

    float v1[8], a1[8];
    #pragma unroll
    for (int u = 0; u < 8; ++u) { v1[u] = 0.f; a1[u] = 0.f; }
    unsigned sm = 0;
    int anyprev = 0;
    float v_out = 0.f, acco = 0.f;

    #pragma unroll 1
    for (int t0 = 0; t0 < T_; t0 += PF) {
        #pragma unroll
        for (int j = 0; j < PF; ++j) {
            const int t = t0 + j;
            float cur[8];
            #pragma unroll
            for (int w = 0; w < 4; ++w) {
                int wv = q[j][w];
                cur[2 * w]     = __builtin_bit_cast(float, wv << 16);
                cur[2 * w + 1] = __builtin_bit_cast(float, wv & 0xffff0000);
            }
            if (t + PF < T_) q[j] = LOADQ(t + PF);

            if (anyprev) {           // rare path: recurrent input from prev spikes
                #pragma unroll
                for (int u = 0; u < 8; ++u) {
                    unsigned long long mu = __ballot((sm >> u) & 1u);
                    while (mu) {
                        int jl = __ffsll(mu) - 1; mu &= mu - 1;
                        const float* wr = wrecT + (size_t)(jl * 8 + u) * NHID + lane * 8;
                        f32x4 wa = *(const f32x4*)wr;
                        f32x4 wb = *(const f32x4*)(wr + 4);
                        cur[0] += wa[0]; cur[1] += wa[1]; cur[2] += wa[2]; cur[3] += wa[3];
                        cur[4] += wb[0]; cur[5] += wb[1]; cur[6] += wb[2]; cur[7] += wb[3];
                    }
                }
            }

            unsigned nm = 0;
            #pragma unroll
            for (int u = 0; u < 8; ++u) {
                float sp = ((sm >> u) & 1u) ? 1.0f : 0.0f;
                v1[u] = 0.95f * v1[u] + 0.05f * cur[u] - sp;
                a1[u] = 0.85f * a1[u] + 0.15f * sp;
                if (v1[u] - (1.0f + 0.05f * a1[u]) > 0.0f) nm |= (1u << u);
            }

            unsigned long long anyb = __ballot(nm != 0u);
            float io = 0.0f;
            if (anyb) {              // rare path: readout current from spikes
                #pragma unroll
                for (int u = 0; u < 8; ++u) {
                    unsigned long long mu = __ballot((nm >> u) & 1u);
                    while (mu) {
                        int jl = __ffsll(mu) - 1; mu &= mu - 1;
                        int unit = jl * 8 + u;
                        if (lane < NOUT) io += w_out[(size_t)lane * NHID + unit];
                    }
                }
            }

            v_out = 0.9f * v_out + io;
            float so = (v_out - 1.0f > 0.0f) ? 1.0f : 0.0f;
            v_out -= so;
            acco += v_out;

            sm = nm;
            anyprev = (anyb != 0ull);
        }
    }

    if (lane < NOUT) out[b * NOUT + lane] = acco * (1.0f / 250.0f);
}

// ---------------- launcher ----------------
extern "C" void kernel_launch(void* const* d_in, const int* in_sizes, int n_in,
                              void* d_out, int out_size, void* d_ws, size_t ws_size,
                              hipStream_t stream)
{
    const float* x     = (const float*)d_in[0];
    const float* w_kan = (const float*)d_in[1];
    const float* d1    = (const float*)d_in[2];
    const float* d2    = (const float*)d_in[3];
    const float* d3    = (const float*)d_in[4];
    const float* w_rec = (const float*)d_in[5];
    const float* w_out = (const float*)d_in[6];
    float* out = (float*)d_out;

    char*   ws    = (char*)d_ws;
    __bf16* iin   = (__bf16*)ws;
    int*    Apack = (int*)(ws + APACK_OFF);
    int*    Bpack = (int*)(ws + BPACK_OFF);
    float*  wrecT = (float*)(ws + WRECT_OFF);

    kan_pack<<<dim3((BPACK_WORDS + 255) / 256), 256, 0, stream>>>(
        w_kan, d1, d2, d3, w_rec, Bpack, wrecT);
    kan_packa<<<dim3(MC_N * KT_N), 256, 0, stream>>>(x, Apack);
    kan_gemm<<<dim3(NHID / 128, M_TOT / 128), 256, 0, stream>>>(Apack, Bpack, iin);
    kan_scan<<<dim3(B_), 64, 0, stream>>>(iin, wrecT, w_out, out);
}